// Round 2
// baseline (197.121 us; speedup 1.0000x reference)
//
#include <hip/hip_runtime.h>
#include <hip/hip_bf16.h>

// Problem constants (fixed by setup_inputs)
constexpr int B = 512;   // batch
constexpr int D = 4096;  // D_vis
constexpr int E = 1024;  // embed dim
constexpr int N = 512;   // negatives

typedef __attribute__((ext_vector_type(8))) short bf16x8;   // 8 bf16 = 4 VGPRs
typedef __attribute__((ext_vector_type(4))) float f32x4;

__device__ __forceinline__ unsigned short f2bf(float f) {
    __hip_bfloat16 h = __float2bfloat16(f);   // RTNE
    return *reinterpret_cast<unsigned short*>(&h);
}

// ---------------------------------------------------------------------------
// Kernel 0: f32 -> bf16 convert (grid-stride-free exact cover, 8 elems/thread)
// ---------------------------------------------------------------------------
__global__ __launch_bounds__(256) void cvt_bf16(
    const float* __restrict__ src, unsigned short* __restrict__ dst)
{
    const int i = (blockIdx.x * 256 + threadIdx.x) * 8;
    float4 v0 = *(const float4*)(src + i);
    float4 v1 = *(const float4*)(src + i + 4);
    bf16x8 o;
    o[0] = (short)f2bf(v0.x); o[1] = (short)f2bf(v0.y);
    o[2] = (short)f2bf(v0.z); o[3] = (short)f2bf(v0.w);
    o[4] = (short)f2bf(v1.x); o[5] = (short)f2bf(v1.y);
    o[6] = (short)f2bf(v1.z); o[7] = (short)f2bf(v1.w);
    *(bf16x8*)(dst + i) = o;
}

// ---------------------------------------------------------------------------
// Kernel 1: vf_emb[b][e] = sum_d vf[b,d]*W[e,d] + bias[e], fp32 out to ws.
// One wave per block; wave tile 64(m=b) x 32(n=e); K=4096 in steps of 32.
// A-frag: A[m=lane&15][k=quad*8+j]; B-frag: B[k=quad*8+j][n=lane&15] (=W row).
// C/D: col=lane&15, row=quad*4+reg  [measured layouts, m89]
// ---------------------------------------------------------------------------
__global__ __launch_bounds__(64) void gemm_emb(
    const unsigned short* __restrict__ vf,    // [B, D] bf16 bits (ws copy)
    const unsigned short* __restrict__ W,     // [E, D] bf16 bits (ws copy)
    const float* __restrict__ bias,           // [E] f32
    float* __restrict__ emb)                  // [B, E] f32
{
    const int lane = threadIdx.x;
    const int m0 = blockIdx.y * 64;   // b tile
    const int n0 = blockIdx.x * 32;   // e tile
    const int r16 = lane & 15;
    const int quad = lane >> 4;

    f32x4 acc[4][2] = {};

    const unsigned short* ap = vf + (size_t)(m0 + r16) * D + quad * 8;
    const unsigned short* bp = W  + (size_t)(n0 + r16) * D + quad * 8;

    for (int k0 = 0; k0 < D; k0 += 32) {
        bf16x8 a[4], bb[2];
        #pragma unroll
        for (int i = 0; i < 4; ++i)
            a[i] = *(const bf16x8*)(ap + (size_t)i * 16 * D + k0);
        #pragma unroll
        for (int j = 0; j < 2; ++j)
            bb[j] = *(const bf16x8*)(bp + (size_t)j * 16 * D + k0);
        #pragma unroll
        for (int i = 0; i < 4; ++i)
            #pragma unroll
            for (int j = 0; j < 2; ++j)
                acc[i][j] = __builtin_amdgcn_mfma_f32_16x16x32_bf16(
                    a[i], bb[j], acc[i][j], 0, 0, 0);
    }

    #pragma unroll
    for (int j = 0; j < 2; ++j) {
        const int col = n0 + j * 16 + r16;
        const float bv = bias[col];
        #pragma unroll
        for (int i = 0; i < 4; ++i) {
            const int row = m0 + i * 16 + quad * 4;
            #pragma unroll
            for (int r = 0; r < 4; ++r)
                emb[(size_t)(row + r) * E + col] = acc[i][j][r] + bv;
        }
    }
}

// ---------------------------------------------------------------------------
// Kernel 2: out[b][1+n] = -sqrt( sum_e relu(n_lfs[n,e] - emb[b,e])^2 )
// Block: 256 threads, tile 32(b) x 32(n), 2x2 per thread, E chunked by 64
// into LDS (stride 66 -> float2-aligned rows, <=2-way bank aliasing = free).
// ---------------------------------------------------------------------------
__global__ __launch_bounds__(256) void neg_scores(
    const float* __restrict__ emb,    // [B, E] f32
    const float* __restrict__ n_lfs,  // [N, E] f32
    float* __restrict__ out)          // [B, 1+N] f32
{
    constexpr int EC = 64;
    constexpr int LDW = EC + 2;  // 66: even (float2 align), breaks 32-bank stride
    __shared__ float eS[32 * LDW];
    __shared__ float nS[32 * LDW];

    const int t  = threadIdx.x;
    const int b0 = blockIdx.y * 32;
    const int n0 = blockIdx.x * 32;
    const int sr = t >> 3;          // staging row 0..31
    const int sc = (t & 7) * 8;     // staging col 0..56
    const int ty = t >> 4;          // 0..15
    const int tx = t & 15;          // 0..15
    const int bl = ty * 2;          // local b pair
    const int nl = tx * 2;          // local n pair

    float acc00 = 0.f, acc01 = 0.f, acc10 = 0.f, acc11 = 0.f;

    for (int e0 = 0; e0 < E; e0 += EC) {
        __syncthreads();
        // stage emb chunk (f32, coalesced float4 x2)
        const float* ep = emb + (size_t)(b0 + sr) * E + e0 + sc;
        float4 v0 = *(const float4*)(ep);
        float4 v1 = *(const float4*)(ep + 4);
        float* ed = &eS[sr * LDW + sc];
        ed[0] = v0.x; ed[1] = v0.y; ed[2] = v0.z; ed[3] = v0.w;
        ed[4] = v1.x; ed[5] = v1.y; ed[6] = v1.z; ed[7] = v1.w;
        // stage n_lfs chunk (f32)
        const float* npp = n_lfs + (size_t)(n0 + sr) * E + e0 + sc;
        float4 w0 = *(const float4*)(npp);
        float4 w1 = *(const float4*)(npp + 4);
        float* nd = &nS[sr * LDW + sc];
        nd[0] = w0.x; nd[1] = w0.y; nd[2] = w0.z; nd[3] = w0.w;
        nd[4] = w1.x; nd[5] = w1.y; nd[6] = w1.z; nd[7] = w1.w;
        __syncthreads();

        const float* eb0 = &eS[(size_t)bl * LDW];
        const float* eb1 = &eS[(size_t)(bl + 1) * LDW];
        const float* nb0 = &nS[(size_t)nl * LDW];
        const float* nb1 = &nS[(size_t)(nl + 1) * LDW];
        #pragma unroll 8
        for (int e = 0; e < EC; e += 2) {
            float2 a0 = *(const float2*)&eb0[e];
            float2 a1 = *(const float2*)&eb1[e];
            float2 c0 = *(const float2*)&nb0[e];
            float2 c1 = *(const float2*)&nb1[e];
            float d;
            d = c0.x - a0.x; d = fmaxf(d, 0.f); acc00 = fmaf(d, d, acc00);
            d = c0.y - a0.y; d = fmaxf(d, 0.f); acc00 = fmaf(d, d, acc00);
            d = c1.x - a0.x; d = fmaxf(d, 0.f); acc01 = fmaf(d, d, acc01);
            d = c1.y - a0.y; d = fmaxf(d, 0.f); acc01 = fmaf(d, d, acc01);
            d = c0.x - a1.x; d = fmaxf(d, 0.f); acc10 = fmaf(d, d, acc10);
            d = c0.y - a1.y; d = fmaxf(d, 0.f); acc10 = fmaf(d, d, acc10);
            d = c1.x - a1.x; d = fmaxf(d, 0.f); acc11 = fmaf(d, d, acc11);
            d = c1.y - a1.y; d = fmaxf(d, 0.f); acc11 = fmaf(d, d, acc11);
        }
    }

    const size_t ob = (size_t)(b0 + bl);
    const int on = n0 + nl;
    out[ob * 513 + 1 + on]           = -sqrtf(acc00);
    out[ob * 513 + 1 + on + 1]       = -sqrtf(acc01);
    out[(ob + 1) * 513 + 1 + on]     = -sqrtf(acc10);
    out[(ob + 1) * 513 + 1 + on + 1] = -sqrtf(acc11);
}

// ---------------------------------------------------------------------------
// Kernel 3: out[b][0] = -sqrt( sum_e relu(p_lfs[b,e] - emb[b,e])^2 )
// One wave per b; shuffle reduction over 64 lanes.
// ---------------------------------------------------------------------------
__global__ __launch_bounds__(64) void pos_scores(
    const float* __restrict__ emb,    // [B, E] f32
    const float* __restrict__ p_lfs,  // [B, E] f32
    float* __restrict__ out)          // [B, 1+N] f32
{
    const int b = blockIdx.x;
    const int lane = threadIdx.x;
    float acc = 0.f;
    #pragma unroll
    for (int e0 = 0; e0 < E; e0 += 64) {
        const int e = e0 + lane;
        const float p = p_lfs[(size_t)b * E + e];
        float d = p - emb[(size_t)b * E + e];
        d = fmaxf(d, 0.f);
        acc = fmaf(d, d, acc);
    }
    #pragma unroll
    for (int off = 32; off > 0; off >>= 1)
        acc += __shfl_down(acc, off);
    if (lane == 0)
        out[(size_t)b * 513] = -sqrtf(acc);
}

extern "C" void kernel_launch(void* const* d_in, const int* in_sizes, int n_in,
                              void* d_out, int out_size, void* d_ws, size_t ws_size,
                              hipStream_t stream) {
    const float* vf    = (const float*)d_in[0];  // [512,4096] f32
    const float* p_lfs = (const float*)d_in[1];  // [512,1024] f32
    const float* n_lfs = (const float*)d_in[2];  // [512,1024] f32
    const float* W     = (const float*)d_in[3];  // [1024,4096] f32
    const float* bias  = (const float*)d_in[4];  // [1024] f32
    float* out = (float*)d_out;                  // [512,513] f32

    char* ws = (char*)d_ws;
    float*          emb = (float*)ws;                        // 2 MB
    unsigned short* vfB = (unsigned short*)(ws + (2 << 20)); // 4 MB
    unsigned short* WB  = (unsigned short*)(ws + (6 << 20)); // 8 MB

    // f32 -> bf16 copies for MFMA (2% abs threshold sanctions bf16 compute)
    cvt_bf16<<<(B * D) / 2048, 256, 0, stream>>>(vf, vfB);
    cvt_bf16<<<(E * D) / 2048, 256, 0, stream>>>(W, WB);

    dim3 g1(E / 32, B / 64);   // (32, 8) = 256 blocks, 64 thr
    gemm_emb<<<g1, 64, 0, stream>>>(vfB, WB, bias, emb);

    dim3 g2(N / 32, B / 32);   // (16, 16) = 256 blocks, 256 thr
    neg_scores<<<g2, 256, 0, stream>>>(emb, n_lfs, out);

    pos_scores<<<B, 64, 0, stream>>>(emb, p_lfs, out);
}

// Round 3
// 163.473 us; speedup vs baseline: 1.2058x; 1.2058x over previous
//
#include <hip/hip_runtime.h>
#include <hip/hip_bf16.h>

// Problem constants (fixed by setup_inputs)
constexpr int B = 512;   // batch
constexpr int D = 4096;  // D_vis
constexpr int E = 1024;  // embed dim
constexpr int N = 512;   // negatives
constexpr int KS = 4;    // GEMM K-split factor
constexpr int KC = D / KS;  // 1024 K per split

typedef __attribute__((ext_vector_type(8))) short bf16x8;   // 8 bf16 = 4 VGPRs
typedef __attribute__((ext_vector_type(4))) float f32x4;
typedef float v2f __attribute__((ext_vector_type(2)));

__device__ __forceinline__ unsigned short f2bf(float f) {
    __hip_bfloat16 h = __float2bfloat16(f);   // RTNE
    return *reinterpret_cast<unsigned short*>(&h);
}

// ---------------------------------------------------------------------------
// Kernel 0: f32 -> bf16 convert for BOTH vf and W in one dispatch.
// vf: 2M elems -> blocks [0,1024); W: 4M elems -> blocks [1024,3072).
// ---------------------------------------------------------------------------
__global__ __launch_bounds__(256) void cvt_all(
    const float* __restrict__ vf, const float* __restrict__ W,
    unsigned short* __restrict__ vfB, unsigned short* __restrict__ WB)
{
    const int bid = blockIdx.x;
    const float* src;
    unsigned short* dst;
    int i;
    if (bid < 1024) { src = vf; dst = vfB; i = (bid * 256 + threadIdx.x) * 8; }
    else           { src = W;  dst = WB;  i = ((bid - 1024) * 256 + threadIdx.x) * 8; }
    float4 v0 = *(const float4*)(src + i);
    float4 v1 = *(const float4*)(src + i + 4);
    bf16x8 o;
    o[0] = (short)f2bf(v0.x); o[1] = (short)f2bf(v0.y);
    o[2] = (short)f2bf(v0.z); o[3] = (short)f2bf(v0.w);
    o[4] = (short)f2bf(v1.x); o[5] = (short)f2bf(v1.y);
    o[6] = (short)f2bf(v1.z); o[7] = (short)f2bf(v1.w);
    *(bf16x8*)(dst + i) = o;
}

// ---------------------------------------------------------------------------
// Kernel 1: K-split GEMM. part[ks][b][e] = sum_{k in split ks} vf[b,k]*W[e,k]
// One wave per block; wave tile 32(b) x 32(e); grid (E/32, B/32, KS) = 2048
// waves = 8 waves/CU = 2/SIMD (vs round-2's 1 wave/CU -> latency exposed).
// A-frag: A[m=lane&15][k=quad*8+j]; B-frag: B[k=quad*8+j][n=lane&15].
// C/D: col=lane&15, row=quad*4+reg  [verified by round-2 pass]
// ---------------------------------------------------------------------------
__global__ __launch_bounds__(64) void gemm_split(
    const unsigned short* __restrict__ vf,    // [B, D] bf16 bits
    const unsigned short* __restrict__ W,     // [E, D] bf16 bits
    float* __restrict__ part)                 // [KS, B, E] f32
{
    const int lane = threadIdx.x;
    const int n0 = blockIdx.x * 32;   // e tile
    const int m0 = blockIdx.y * 32;   // b tile
    const int ks = blockIdx.z;
    const int r16 = lane & 15;
    const int quad = lane >> 4;

    f32x4 acc[2][2] = {};

    const unsigned short* ap = vf + (size_t)(m0 + r16) * D + quad * 8;
    const unsigned short* bp = W  + (size_t)(n0 + r16) * D + quad * 8;
    const int kbeg = ks * KC;

    #pragma unroll 4
    for (int k0 = kbeg; k0 < kbeg + KC; k0 += 32) {
        bf16x8 a[2], bb[2];
        #pragma unroll
        for (int i = 0; i < 2; ++i)
            a[i] = *(const bf16x8*)(ap + (size_t)i * 16 * D + k0);
        #pragma unroll
        for (int j = 0; j < 2; ++j)
            bb[j] = *(const bf16x8*)(bp + (size_t)j * 16 * D + k0);
        #pragma unroll
        for (int i = 0; i < 2; ++i)
            #pragma unroll
            for (int j = 0; j < 2; ++j)
                acc[i][j] = __builtin_amdgcn_mfma_f32_16x16x32_bf16(
                    a[i], bb[j], acc[i][j], 0, 0, 0);
    }

    float* pout = part + (size_t)ks * B * E;
    #pragma unroll
    for (int j = 0; j < 2; ++j) {
        const int col = n0 + j * 16 + r16;
        #pragma unroll
        for (int i = 0; i < 2; ++i) {
            const int row = m0 + i * 16 + quad * 4;
            #pragma unroll
            for (int r = 0; r < 4; ++r)
                pout[(size_t)(row + r) * E + col] = acc[i][j][r];
        }
    }
}

// ---------------------------------------------------------------------------
// Kernel 2: emb[b][e] = sum_ks part[ks][b][e] + bias[e]
// ---------------------------------------------------------------------------
__global__ __launch_bounds__(256) void reduce_emb(
    const float* __restrict__ part, const float* __restrict__ bias,
    float* __restrict__ emb)
{
    const int idx = (blockIdx.x * 256 + threadIdx.x) * 4;
    const int col = idx & (E - 1);
    float4 s = *(const float4*)(bias + col);
    #pragma unroll
    for (int ks = 0; ks < KS; ++ks) {
        float4 p = *(const float4*)(part + (size_t)ks * B * E + idx);
        s.x += p.x; s.y += p.y; s.z += p.z; s.w += p.w;
    }
    *(float4*)(emb + idx) = s;
}

// ---------------------------------------------------------------------------
// Kernel 3: scores. grid (N/32 + 1, B/32).
//   x in [0,16): out[b][1+n] = -sqrt(sum_e relu(n_lfs[n,e]-emb[b,e])^2)
//                32(b) x 32(n) tile, 2x2/thread, EC=128 LDS chunks,
//                v2f inner loop (targets v_pk_fma_f32 / v_pk_max_f32).
//   x == 16:     out[b][0] = positive scores for 32 b-rows.
// ---------------------------------------------------------------------------
__global__ __launch_bounds__(256) void scores(
    const float* __restrict__ emb,    // [B, E] f32
    const float* __restrict__ n_lfs,  // [N, E] f32
    const float* __restrict__ p_lfs,  // [B, E] f32
    float* __restrict__ out)          // [B, 1+N] f32
{
    const int t  = threadIdx.x;
    const int b0 = blockIdx.y * 32;

    if (blockIdx.x == N / 32) {
        // ---- positive scores for rows b0..b0+31 ----
        const int r = t >> 3;        // 0..31
        const int g = t & 7;         // 8 threads per row
        const float* pr = p_lfs + (size_t)(b0 + r) * E;
        const float* er = emb   + (size_t)(b0 + r) * E;
        float acc = 0.f;
        for (int e = g * 4; e < E; e += 32) {
            float4 p = *(const float4*)(pr + e);
            float4 v = *(const float4*)(er + e);
            float d;
            d = p.x - v.x; d = fmaxf(d, 0.f); acc = fmaf(d, d, acc);
            d = p.y - v.y; d = fmaxf(d, 0.f); acc = fmaf(d, d, acc);
            d = p.z - v.z; d = fmaxf(d, 0.f); acc = fmaf(d, d, acc);
            d = p.w - v.w; d = fmaxf(d, 0.f); acc = fmaf(d, d, acc);
        }
        #pragma unroll
        for (int off = 4; off; off >>= 1) acc += __shfl_down(acc, off, 8);
        if (g == 0) out[(size_t)(b0 + r) * 513] = -sqrtf(acc);
        return;
    }

    // ---- negative scores, 32x32 tile ----
    constexpr int EC = 128;
    constexpr int LDW = EC + 2;  // even (8B-aligned rows), breaks 32-bank stride
    __shared__ float eS[32 * LDW];
    __shared__ float nS[32 * LDW];

    const int n0 = blockIdx.x * 32;
    const int sr = t >> 3;           // staging row 0..31
    const int sc = (t & 7) * 16;     // staging col 0..112
    const int ty = t >> 4;           // 0..15
    const int tx = t & 15;           // 0..15
    const int bl = ty * 2;           // local b pair
    const int nl = tx * 2;           // local n pair

    const v2f z = {0.f, 0.f};
    v2f acc00 = z, acc01 = z, acc10 = z, acc11 = z;

    for (int e0 = 0; e0 < E; e0 += EC) {
        __syncthreads();
        const float* ep  = emb   + (size_t)(b0 + sr) * E + e0 + sc;
        const float* npp = n_lfs + (size_t)(n0 + sr) * E + e0 + sc;
        float* ed = &eS[sr * LDW + sc];
        float* nd = &nS[sr * LDW + sc];
        #pragma unroll
        for (int q = 0; q < 4; ++q) {
            float4 v = *(const float4*)(ep + q * 4);
            float4 w = *(const float4*)(npp + q * 4);
            ed[q * 4 + 0] = v.x; ed[q * 4 + 1] = v.y;
            ed[q * 4 + 2] = v.z; ed[q * 4 + 3] = v.w;
            nd[q * 4 + 0] = w.x; nd[q * 4 + 1] = w.y;
            nd[q * 4 + 2] = w.z; nd[q * 4 + 3] = w.w;
        }
        __syncthreads();

        const float* eb0 = &eS[(size_t)bl * LDW];
        const float* eb1 = &eS[(size_t)(bl + 1) * LDW];
        const float* nb0 = &nS[(size_t)nl * LDW];
        const float* nb1 = &nS[(size_t)(nl + 1) * LDW];
        #pragma unroll 16
        for (int e = 0; e < EC; e += 2) {
            v2f a0 = *(const v2f*)&eb0[e];
            v2f a1 = *(const v2f*)&eb1[e];
            v2f c0 = *(const v2f*)&nb0[e];
            v2f c1 = *(const v2f*)&nb1[e];
            v2f d;
            d = c0 - a0; d = __builtin_elementwise_max(d, z);
            acc00 = __builtin_elementwise_fma(d, d, acc00);
            d = c1 - a0; d = __builtin_elementwise_max(d, z);
            acc01 = __builtin_elementwise_fma(d, d, acc01);
            d = c0 - a1; d = __builtin_elementwise_max(d, z);
            acc10 = __builtin_elementwise_fma(d, d, acc10);
            d = c1 - a1; d = __builtin_elementwise_max(d, z);
            acc11 = __builtin_elementwise_fma(d, d, acc11);
        }
    }

    const size_t ob = (size_t)(b0 + bl);
    const int on = n0 + nl;
    out[ob * 513 + 1 + on]           = -sqrtf(acc00.x + acc00.y);
    out[ob * 513 + 1 + on + 1]       = -sqrtf(acc01.x + acc01.y);
    out[(ob + 1) * 513 + 1 + on]     = -sqrtf(acc10.x + acc10.y);
    out[(ob + 1) * 513 + 1 + on + 1] = -sqrtf(acc11.x + acc11.y);
}

extern "C" void kernel_launch(void* const* d_in, const int* in_sizes, int n_in,
                              void* d_out, int out_size, void* d_ws, size_t ws_size,
                              hipStream_t stream) {
    const float* vf    = (const float*)d_in[0];  // [512,4096] f32
    const float* p_lfs = (const float*)d_in[1];  // [512,1024] f32
    const float* n_lfs = (const float*)d_in[2];  // [512,1024] f32
    const float* W     = (const float*)d_in[3];  // [1024,4096] f32
    const float* bias  = (const float*)d_in[4];  // [1024] f32
    float* out = (float*)d_out;                  // [512,513] f32

    // ws layout (20 MB total):
    //   [0,  8MB): part  f32 [KS,512,1024]
    //   [8, 12MB): vfB  bf16 [512,4096]  (dead after gemm)
    //   [12,20MB): WB   bf16 [1024,4096]
    //   [8, 10MB): emb  f32 [512,1024]   (overlays dead vfB; written by reduce)
    char* ws = (char*)d_ws;
    float*          part = (float*)ws;
    unsigned short* vfB  = (unsigned short*)(ws + ((size_t)8 << 20));
    unsigned short* WB   = (unsigned short*)(ws + ((size_t)12 << 20));
    float*          emb  = (float*)(ws + ((size_t)8 << 20));

    cvt_all<<<3072, 256, 0, stream>>>(vf, W, vfB, WB);

    dim3 g1(E / 32, B / 32, KS);   // (32, 16, 4) = 2048 one-wave blocks
    gemm_split<<<g1, 64, 0, stream>>>(vfB, WB, part);

    reduce_emb<<<(B * E) / 1024, 256, 0, stream>>>(part, bias, emb);

    dim3 g3(N / 32 + 1, B / 32);   // (17, 16); x==16 -> positive scores
    scores<<<g3, 256, 0, stream>>>(emb, n_lfs, p_lfs, out);
}

// Round 4
// 146.275 us; speedup vs baseline: 1.3476x; 1.1176x over previous
//
#include <hip/hip_runtime.h>
#include <hip/hip_bf16.h>

// Problem constants (fixed by setup_inputs)
constexpr int B = 512;   // batch
constexpr int D = 4096;  // D_vis
constexpr int E = 1024;  // embed dim
constexpr int N = 512;   // negatives
constexpr int KS = 8;    // GEMM K-split factor
constexpr int KC = D / KS;   // 512 K per split
constexpr int ES = 8;    // scores E-split factor
constexpr int EC = E / ES;   // 128 e per scores block

typedef __attribute__((ext_vector_type(8))) short bf16x8;   // 8 bf16 = 4 VGPRs
typedef __attribute__((ext_vector_type(4))) float f32x4;
typedef float v2f __attribute__((ext_vector_type(2)));

__device__ __forceinline__ unsigned short f2bf(float f) {
    __hip_bfloat16 h = __float2bfloat16(f);   // RTNE
    return *reinterpret_cast<unsigned short*>(&h);
}

// ---------------------------------------------------------------------------
// Kernel 0: f32 -> bf16 convert for BOTH vf and W in one dispatch.
// ---------------------------------------------------------------------------
__global__ __launch_bounds__(256) void cvt_all(
    const float* __restrict__ vf, const float* __restrict__ W,
    unsigned short* __restrict__ vfB, unsigned short* __restrict__ WB)
{
    const int bid = blockIdx.x;
    const float* src;
    unsigned short* dst;
    int i;
    if (bid < 1024) { src = vf; dst = vfB; i = (bid * 256 + threadIdx.x) * 8; }
    else           { src = W;  dst = WB;  i = ((bid - 1024) * 256 + threadIdx.x) * 8; }
    float4 v0 = *(const float4*)(src + i);
    float4 v1 = *(const float4*)(src + i + 4);
    bf16x8 o;
    o[0] = (short)f2bf(v0.x); o[1] = (short)f2bf(v0.y);
    o[2] = (short)f2bf(v0.z); o[3] = (short)f2bf(v0.w);
    o[4] = (short)f2bf(v1.x); o[5] = (short)f2bf(v1.y);
    o[6] = (short)f2bf(v1.z); o[7] = (short)f2bf(v1.w);
    *(bf16x8*)(dst + i) = o;
}

// ---------------------------------------------------------------------------
// Kernel 1: K-split GEMM, wave tile 64(m) x 32(n), KS=8.
// grid (E/32, B/64, KS) = (32,8,8) = 2048 one-wave blocks = 8 waves/CU.
// A-frag: A[m=lane&15][k=quad*8+j]; B-frag: B[k=quad*8+j][n=lane&15].
// C/D: col=lane&15, row=quad*4+reg  [verified rounds 2-3]
// ---------------------------------------------------------------------------
__global__ __launch_bounds__(64) void gemm_split(
    const unsigned short* __restrict__ vf,    // [B, D] bf16 bits
    const unsigned short* __restrict__ W,     // [E, D] bf16 bits
    float* __restrict__ part)                 // [KS, B, E] f32
{
    const int lane = threadIdx.x;
    const int n0 = blockIdx.x * 32;   // e tile
    const int m0 = blockIdx.y * 64;   // b tile
    const int ks = blockIdx.z;
    const int r16 = lane & 15;
    const int quad = lane >> 4;

    f32x4 acc[4][2] = {};

    const unsigned short* ap = vf + (size_t)(m0 + r16) * D + quad * 8;
    const unsigned short* bp = W  + (size_t)(n0 + r16) * D + quad * 8;
    const int kbeg = ks * KC;

    #pragma unroll 4
    for (int k0 = kbeg; k0 < kbeg + KC; k0 += 32) {
        bf16x8 a[4], bb[2];
        #pragma unroll
        for (int i = 0; i < 4; ++i)
            a[i] = *(const bf16x8*)(ap + (size_t)i * 16 * D + k0);
        #pragma unroll
        for (int j = 0; j < 2; ++j)
            bb[j] = *(const bf16x8*)(bp + (size_t)j * 16 * D + k0);
        #pragma unroll
        for (int i = 0; i < 4; ++i)
            #pragma unroll
            for (int j = 0; j < 2; ++j)
                acc[i][j] = __builtin_amdgcn_mfma_f32_16x16x32_bf16(
                    a[i], bb[j], acc[i][j], 0, 0, 0);
    }

    float* pout = part + (size_t)ks * B * E;
    #pragma unroll
    for (int j = 0; j < 2; ++j) {
        const int col = n0 + j * 16 + r16;
        #pragma unroll
        for (int i = 0; i < 4; ++i) {
            const int row = m0 + i * 16 + quad * 4;
            #pragma unroll
            for (int r = 0; r < 4; ++r)
                pout[(size_t)(row + r) * E + col] = acc[i][j][r];
        }
    }
}

// ---------------------------------------------------------------------------
// Kernel 2: emb[b][e] = sum_ks part[ks][b][e] + bias[e]
// ---------------------------------------------------------------------------
__global__ __launch_bounds__(256) void reduce_emb(
    const float* __restrict__ part, const float* __restrict__ bias,
    float* __restrict__ emb)
{
    const int idx = (blockIdx.x * 256 + threadIdx.x) * 4;
    const int col = idx & (E - 1);
    float4 s = *(const float4*)(bias + col);
    #pragma unroll
    for (int ks = 0; ks < KS; ++ks) {
        float4 p = *(const float4*)(part + (size_t)ks * B * E + idx);
        s.x += p.x; s.y += p.y; s.z += p.z; s.w += p.w;
    }
    *(float4*)(emb + idx) = s;
}

// ---------------------------------------------------------------------------
// Kernel 3: neg-score partials.
// grid (N/64, B/64, ES) = (8,8,8) = 512 blocks = 2 blocks/CU = 8 waves/CU.
// Tile 64(b) x 64(n), 4x4 v2f accs/thread, one EC=128 chunk per block
// (staged once -> single barrier, no in-loop barriers).
// LDS: LDW=130 (even: 8B-aligned rows). Inner-loop row mapping tx+16c makes
// the 16 strided b64 reads hit banks 2*tx (+1) -> all 32 banks once each.
// pn[bz][b][n] = partial sum of relu(n-e)^2 over e-chunk bz.
// ---------------------------------------------------------------------------
__global__ __launch_bounds__(256, 2) void scores_part(
    const float* __restrict__ emb,    // [B, E] f32
    const float* __restrict__ n_lfs,  // [N, E] f32
    float* __restrict__ pn)           // [ES, B, N] f32
{
    constexpr int LDW = EC + 2;  // 130
    __shared__ float eS[64 * LDW];
    __shared__ float nS[64 * LDW];

    const int t  = threadIdx.x;
    const int n0 = blockIdx.x * 64;
    const int b0 = blockIdx.y * 64;
    const int e0 = blockIdx.z * EC;

    // ---- stage one 64x128 chunk of emb and n_lfs (float2 LDS writes: 2-way max) ----
    {
        const int row = t >> 2;            // 0..63
        const int cb  = (t & 3) * 32;      // 0,32,64,96
        const float* ep = emb   + (size_t)(b0 + row) * E + e0 + cb;
        const float* np = n_lfs + (size_t)(n0 + row) * E + e0 + cb;
        float* ed = &eS[row * LDW + cb];
        float* nd = &nS[row * LDW + cb];
        #pragma unroll
        for (int q = 0; q < 8; ++q) {
            float4 v = *(const float4*)(ep + q * 4);
            float4 w = *(const float4*)(np + q * 4);
            *(v2f*)(ed + q * 4)     = (v2f){v.x, v.y};
            *(v2f*)(ed + q * 4 + 2) = (v2f){v.z, v.w};
            *(v2f*)(nd + q * 4)     = (v2f){w.x, w.y};
            *(v2f*)(nd + q * 4 + 2) = (v2f){w.z, w.w};
        }
    }
    __syncthreads();

    const int ty = t >> 4;   // 0..15 -> b rows ty+16r
    const int tx = t & 15;   // 0..15 -> n rows tx+16c

    const v2f z = {0.f, 0.f};
    v2f acc[4][4] = {{z,z,z,z},{z,z,z,z},{z,z,z,z},{z,z,z,z}};

    #pragma unroll 4
    for (int e = 0; e < EC; e += 2) {
        v2f a[4], c[4];
        #pragma unroll
        for (int r = 0; r < 4; ++r)
            a[r] = *(const v2f*)&eS[(ty + 16 * r) * LDW + e];
        #pragma unroll
        for (int q = 0; q < 4; ++q)
            c[q] = *(const v2f*)&nS[(tx + 16 * q) * LDW + e];
        #pragma unroll
        for (int r = 0; r < 4; ++r)
            #pragma unroll
            for (int q = 0; q < 4; ++q) {
                v2f d = c[q] - a[r];
                d = __builtin_elementwise_max(d, z);
                acc[r][q] = __builtin_elementwise_fma(d, d, acc[r][q]);
            }
    }

    float* po = pn + (size_t)blockIdx.z * B * N;
    #pragma unroll
    for (int r = 0; r < 4; ++r) {
        const size_t ob = (size_t)(b0 + ty + 16 * r) * N;
        #pragma unroll
        for (int q = 0; q < 4; ++q)
            po[ob + n0 + tx + 16 * q] = acc[r][q].x + acc[r][q].y;
    }
}

// ---------------------------------------------------------------------------
// Kernel 4: final scores.
//   bx < 1024: out[b][1+n] = -sqrt(sum_z pn[z][b][n])   (one thread per (b,n))
//   bx >= 1024: positive scores, 32 b-rows per block (8 threads/row).
// ---------------------------------------------------------------------------
__global__ __launch_bounds__(256) void scores_final(
    const float* __restrict__ pn,     // [ES, B, N]
    const float* __restrict__ emb,    // [B, E]
    const float* __restrict__ p_lfs,  // [B, E]
    float* __restrict__ out)          // [B, 1+N]
{
    const int t = threadIdx.x;
    if (blockIdx.x < 1024) {
        const int i = blockIdx.x * 256 + t;       // 0..B*N-1
        const int b = i >> 9;                     // /N
        const int n = i & (N - 1);
        float s = 0.f;
        #pragma unroll
        for (int z = 0; z < ES; ++z)
            s += pn[(size_t)z * B * N + i];
        out[(size_t)b * 513 + 1 + n] = -sqrtf(s);
        return;
    }
    // positive scores
    const int b0 = (blockIdx.x - 1024) * 32;
    const int r = t >> 3;        // 0..31
    const int g = t & 7;         // 8 threads per row
    const float* pr = p_lfs + (size_t)(b0 + r) * E;
    const float* er = emb   + (size_t)(b0 + r) * E;
    float acc = 0.f;
    for (int e = g * 4; e < E; e += 32) {
        float4 p = *(const float4*)(pr + e);
        float4 v = *(const float4*)(er + e);
        float d;
        d = p.x - v.x; d = fmaxf(d, 0.f); acc = fmaf(d, d, acc);
        d = p.y - v.y; d = fmaxf(d, 0.f); acc = fmaf(d, d, acc);
        d = p.z - v.z; d = fmaxf(d, 0.f); acc = fmaf(d, d, acc);
        d = p.w - v.w; d = fmaxf(d, 0.f); acc = fmaf(d, d, acc);
    }
    #pragma unroll
    for (int off = 4; off; off >>= 1) acc += __shfl_down(acc, off, 8);
    if (g == 0) out[(size_t)(b0 + r) * 513] = -sqrtf(acc);
}

extern "C" void kernel_launch(void* const* d_in, const int* in_sizes, int n_in,
                              void* d_out, int out_size, void* d_ws, size_t ws_size,
                              hipStream_t stream) {
    const float* vf    = (const float*)d_in[0];  // [512,4096] f32
    const float* p_lfs = (const float*)d_in[1];  // [512,1024] f32
    const float* n_lfs = (const float*)d_in[2];  // [512,1024] f32
    const float* W     = (const float*)d_in[3];  // [1024,4096] f32
    const float* bias  = (const float*)d_in[4];  // [1024] f32
    float* out = (float*)d_out;                  // [512,513] f32

    // ws layout (30 MB peak):
    //   [0, 16MB): pg   f32 [KS,512,1024]  (dead after reduce_emb)
    //   [0,  8MB): pn   f32 [ES,512,512]   (overlays dead pg)
    //   [16,20MB): vfB  bf16 [512,4096]
    //   [20,28MB): WB   bf16 [1024,4096]
    //   [28,30MB): emb  f32 [512,1024]
    char* ws = (char*)d_ws;
    float*          pg  = (float*)ws;
    float*          pn  = (float*)ws;
    unsigned short* vfB = (unsigned short*)(ws + ((size_t)16 << 20));
    unsigned short* WB  = (unsigned short*)(ws + ((size_t)20 << 20));
    float*          emb = (float*)(ws + ((size_t)28 << 20));

    cvt_all<<<3072, 256, 0, stream>>>(vf, W, vfB, WB);

    dim3 g1(E / 32, B / 64, KS);   // (32, 8, 8) = 2048 one-wave blocks
    gemm_split<<<g1, 64, 0, stream>>>(vfB, WB, pg);

    reduce_emb<<<(B * E) / 1024, 256, 0, stream>>>(pg, bias, emb);

    dim3 g3(N / 64, B / 64, ES);   // (8, 8, 8) = 512 blocks
    scores_part<<<g3, 256, 0, stream>>>(emb, n_lfs, pn);

    scores_final<<<1024 + B / 32, 256, 0, stream>>>(pn, emb, p_lfs, out);
}

// Round 5
// 137.215 us; speedup vs baseline: 1.4366x; 1.0660x over previous
//
#include <hip/hip_runtime.h>
#include <hip/hip_bf16.h>

// Problem constants (fixed by setup_inputs)
constexpr int B = 512;   // batch
constexpr int D = 4096;  // D_vis
constexpr int E = 1024;  // embed dim
constexpr int N = 512;   // negatives
constexpr int KS = 4;    // GEMM K-split factor
constexpr int KC = D / KS;      // 1024 K per split
constexpr int NSTEP = KC / 32;  // 32 k-steps per wave
constexpr int ES = 8;    // scores E-split factor
constexpr int EC = E / ES;      // 128 e per scores block

typedef __attribute__((ext_vector_type(8))) short bf16x8;   // 8 bf16 = 4 VGPRs
typedef __attribute__((ext_vector_type(4))) float f32x4;
typedef float v2f __attribute__((ext_vector_type(2)));

typedef __attribute__((address_space(3))) void lds_void;
typedef const __attribute__((address_space(1))) void gbl_void;

__device__ __forceinline__ unsigned short f2bf(float f) {
    __hip_bfloat16 h = __float2bfloat16(f);   // RTNE
    return *reinterpret_cast<unsigned short*>(&h);
}

// ---------------------------------------------------------------------------
// Kernel 0: f32 -> bf16 convert for BOTH vf and W in one dispatch.
// ---------------------------------------------------------------------------
__global__ __launch_bounds__(256) void cvt_all(
    const float* __restrict__ vf, const float* __restrict__ W,
    unsigned short* __restrict__ vfB, unsigned short* __restrict__ WB)
{
    const int bid = blockIdx.x;
    const float* src;
    unsigned short* dst;
    int i;
    if (bid < 1024) { src = vf; dst = vfB; i = (bid * 256 + threadIdx.x) * 8; }
    else           { src = W;  dst = WB;  i = ((bid - 1024) * 256 + threadIdx.x) * 8; }
    float4 v0 = *(const float4*)(src + i);
    float4 v1 = *(const float4*)(src + i + 4);
    bf16x8 o;
    o[0] = (short)f2bf(v0.x); o[1] = (short)f2bf(v0.y);
    o[2] = (short)f2bf(v0.z); o[3] = (short)f2bf(v0.w);
    o[4] = (short)f2bf(v1.x); o[5] = (short)f2bf(v1.y);
    o[6] = (short)f2bf(v1.z); o[7] = (short)f2bf(v1.w);
    *(bf16x8*)(dst + i) = o;
}

// ---------------------------------------------------------------------------
// Kernel 1: K-split GEMM, one wave per block, 64(m) x 64(n) tile, KS=4.
// grid (16,8,4) = 512 blocks = 2 blocks/CU.
// Per-wave global_load_lds double-buffer pipeline (depth 2, no barriers:
// only this wave touches its LDS; sync = s_waitcnt vmcnt(N) only).
// LDS layout: tile stored as 16B chunks, chunk(row, qs) at (row*4+qs)*16,
// holding global (row, q) where q = qs ^ (row&3) ^ ((row>>2)&3).
// -> staging lane L (chunk c*64+L) reads row c*16+(L>>2), q = (L&3)^((L>>2)&3)^((L>>4)&3)
// -> frag ds_read_b128 at row i*16+r16, q=quad is 2-way bank aliased (free, m136).
// A-frag: A[m=lane&15][k=quad*8+j]; B-frag: B[k=quad*8+j][n=lane&15].
// C/D: col=lane&15, row=quad*4+reg  [verified rounds 2-4]
// ---------------------------------------------------------------------------
__global__ __launch_bounds__(64) void gemm_lds(
    const unsigned short* __restrict__ vf,    // [B, D] bf16 bits
    const unsigned short* __restrict__ W,     // [E, D] bf16 bits
    float* __restrict__ part)                 // [KS, B, E] f32
{
    __shared__ unsigned short sA[2][2048];    // 2 bufs x 64x32 bf16 (4 KB each)
    __shared__ unsigned short sB[2][2048];

    const int L  = threadIdx.x;
    const int n0 = blockIdx.x * 64;
    const int m0 = blockIdx.y * 64;
    const int ks = blockIdx.z;

    // ---- staging addresses: per call c (0..3), lane L covers chunk c*64+L ----
    const int subrow = L >> 2;                                  // 0..15
    const int qstg = (L & 3) ^ ((L >> 2) & 3) ^ ((L >> 4) & 3); // swizzled k-group
    const int kbeg = ks * KC;
    const unsigned short* aSrc[4];
    const unsigned short* bSrc[4];
    #pragma unroll
    for (int c = 0; c < 4; ++c) {
        aSrc[c] = vf + (size_t)(m0 + c * 16 + subrow) * D + kbeg + qstg * 8;
        bSrc[c] = W  + (size_t)(n0 + c * 16 + subrow) * D + kbeg + qstg * 8;
    }

    // ---- fragment read offsets ----
    const int r16 = L & 15;
    const int quad = L >> 4;
    const int swz = quad ^ (r16 & 3) ^ ((r16 >> 2) & 3);
    const int aoff = r16 * 64 + swz * 16;   // byte offset within a buffer

    f32x4 acc[4][4] = {};

    auto issue = [&](int step, int buf) {
        const size_t koff = (size_t)step * 32;   // elements
        #pragma unroll
        for (int c = 0; c < 4; ++c) {
            __builtin_amdgcn_global_load_lds(
                (gbl_void*)(aSrc[c] + koff),
                (lds_void*)((char*)&sA[buf][0] + c * 1024), 16, 0, 0);
            __builtin_amdgcn_global_load_lds(
                (gbl_void*)(bSrc[c] + koff),
                (lds_void*)((char*)&sB[buf][0] + c * 1024), 16, 0, 0);
        }
    };

    issue(0, 0);
    issue(1, 1);

    #pragma unroll 1
    for (int s = 0; s < NSTEP; ++s) {
        const int buf = s & 1;
        // wait for buf's 8 loads: steady state outstanding=16 -> vmcnt(8);
        // last step has only its own 8 outstanding -> vmcnt(0).
        if (s == NSTEP - 1) __builtin_amdgcn_s_waitcnt(0x0F70);  // vmcnt(0), exp/lgkm free
        else                __builtin_amdgcn_s_waitcnt(0x0F78);  // vmcnt(8)

        bf16x8 af[4], bf_[4];
        #pragma unroll
        for (int i = 0; i < 4; ++i)
            af[i] = *(const bf16x8*)((const char*)&sA[buf][0] + i * 1024 + aoff);
        #pragma unroll
        for (int j = 0; j < 4; ++j)
            bf_[j] = *(const bf16x8*)((const char*)&sB[buf][0] + j * 1024 + aoff);

        #pragma unroll
        for (int i = 0; i < 4; ++i)
            #pragma unroll
            for (int j = 0; j < 4; ++j)
                acc[i][j] = __builtin_amdgcn_mfma_f32_16x16x32_bf16(
                    af[i], bf_[j], acc[i][j], 0, 0, 0);

        if (s + 2 < NSTEP) issue(s + 2, buf);   // refill the buffer just consumed
    }

    float* po = part + (size_t)ks * B * E;
    #pragma unroll
    for (int j = 0; j < 4; ++j) {
        const int col = n0 + j * 16 + r16;
        #pragma unroll
        for (int i = 0; i < 4; ++i) {
            const int row = m0 + i * 16 + quad * 4;
            #pragma unroll
            for (int r = 0; r < 4; ++r)
                po[(size_t)(row + r) * E + col] = acc[i][j][r];
        }
    }
}

// ---------------------------------------------------------------------------
// Kernel 2: emb[b][e] = sum_ks part[ks][b][e] + bias[e]
// ---------------------------------------------------------------------------
__global__ __launch_bounds__(256) void reduce_emb(
    const float* __restrict__ part, const float* __restrict__ bias,
    float* __restrict__ emb)
{
    const int idx = (blockIdx.x * 256 + threadIdx.x) * 4;
    const int col = idx & (E - 1);
    float4 s = *(const float4*)(bias + col);
    #pragma unroll
    for (int ks = 0; ks < KS; ++ks) {
        float4 p = *(const float4*)(part + (size_t)ks * B * E + idx);
        s.x += p.x; s.y += p.y; s.z += p.z; s.w += p.w;
    }
    *(float4*)(emb + idx) = s;
}

// ---------------------------------------------------------------------------
// Kernel 3: neg-score partials.
// grid (8,8,8) = 512 blocks = 2 blocks/CU = 8 waves/CU.
// Tile 64(b) x 64(n), 4x4 v2f accs/thread, one EC=128 chunk per block.
// ---------------------------------------------------------------------------
__global__ __launch_bounds__(256, 2) void scores_part(
    const float* __restrict__ emb,    // [B, E] f32
    const float* __restrict__ n_lfs,  // [N, E] f32
    float* __restrict__ pn)           // [ES, B, N] f32
{
    constexpr int LDW = EC + 2;  // 130
    __shared__ float eS[64 * LDW];
    __shared__ float nS[64 * LDW];

    const int t  = threadIdx.x;
    const int n0 = blockIdx.x * 64;
    const int b0 = blockIdx.y * 64;
    const int e0 = blockIdx.z * EC;

    {
        const int row = t >> 2;            // 0..63
        const int cb  = (t & 3) * 32;      // 0,32,64,96
        const float* ep = emb   + (size_t)(b0 + row) * E + e0 + cb;
        const float* np = n_lfs + (size_t)(n0 + row) * E + e0 + cb;
        float* ed = &eS[row * LDW + cb];
        float* nd = &nS[row * LDW + cb];
        #pragma unroll
        for (int q = 0; q < 8; ++q) {
            float4 v = *(const float4*)(ep + q * 4);
            float4 w = *(const float4*)(np + q * 4);
            *(v2f*)(ed + q * 4)     = (v2f){v.x, v.y};
            *(v2f*)(ed + q * 4 + 2) = (v2f){v.z, v.w};
            *(v2f*)(nd + q * 4)     = (v2f){w.x, w.y};
            *(v2f*)(nd + q * 4 + 2) = (v2f){w.z, w.w};
        }
    }
    __syncthreads();

    const int ty = t >> 4;   // 0..15 -> b rows ty+16r
    const int tx = t & 15;   // 0..15 -> n rows tx+16c

    const v2f z = {0.f, 0.f};
    v2f acc[4][4] = {{z,z,z,z},{z,z,z,z},{z,z,z,z},{z,z,z,z}};

    #pragma unroll 4
    for (int e = 0; e < EC; e += 2) {
        v2f a[4], c[4];
        #pragma unroll
        for (int r = 0; r < 4; ++r)
            a[r] = *(const v2f*)&eS[(ty + 16 * r) * LDW + e];
        #pragma unroll
        for (int q = 0; q < 4; ++q)
            c[q] = *(const v2f*)&nS[(tx + 16 * q) * LDW + e];
        #pragma unroll
        for (int r = 0; r < 4; ++r)
            #pragma unroll
            for (int q = 0; q < 4; ++q) {
                v2f d = c[q] - a[r];
                d = __builtin_elementwise_max(d, z);
                acc[r][q] = __builtin_elementwise_fma(d, d, acc[r][q]);
            }
    }

    float* po = pn + (size_t)blockIdx.z * B * N;
    #pragma unroll
    for (int r = 0; r < 4; ++r) {
        const size_t ob = (size_t)(b0 + ty + 16 * r) * N;
        #pragma unroll
        for (int q = 0; q < 4; ++q)
            po[ob + n0 + tx + 16 * q] = acc[r][q].x + acc[r][q].y;
    }
}

// ---------------------------------------------------------------------------
// Kernel 4: final scores (negatives reduce + positive scores).
// ---------------------------------------------------------------------------
__global__ __launch_bounds__(256) void scores_final(
    const float* __restrict__ pn,     // [ES, B, N]
    const float* __restrict__ emb,    // [B, E]
    const float* __restrict__ p_lfs,  // [B, E]
    float* __restrict__ out)          // [B, 1+N]
{
    const int t = threadIdx.x;
    if (blockIdx.x < 1024) {
        const int i = blockIdx.x * 256 + t;       // 0..B*N-1
        const int b = i >> 9;                     // /N
        const int n = i & (N - 1);
        float s = 0.f;
        #pragma unroll
        for (int z = 0; z < ES; ++z)
            s += pn[(size_t)z * B * N + i];
        out[(size_t)b * 513 + 1 + n] = -sqrtf(s);
        return;
    }
    const int b0 = (blockIdx.x - 1024) * 32;
    const int r = t >> 3;        // 0..31
    const int g = t & 7;         // 8 threads per row
    const float* pr = p_lfs + (size_t)(b0 + r) * E;
    const float* er = emb   + (size_t)(b0 + r) * E;
    float acc = 0.f;
    for (int e = g * 4; e < E; e += 32) {
        float4 p = *(const float4*)(pr + e);
        float4 v = *(const float4*)(er + e);
        float d;
        d = p.x - v.x; d = fmaxf(d, 0.f); acc = fmaf(d, d, acc);
        d = p.y - v.y; d = fmaxf(d, 0.f); acc = fmaf(d, d, acc);
        d = p.z - v.z; d = fmaxf(d, 0.f); acc = fmaf(d, d, acc);
        d = p.w - v.w; d = fmaxf(d, 0.f); acc = fmaf(d, d, acc);
    }
    #pragma unroll
    for (int off = 4; off; off >>= 1) acc += __shfl_down(acc, off, 8);
    if (g == 0) out[(size_t)(b0 + r) * 513] = -sqrtf(acc);
}

extern "C" void kernel_launch(void* const* d_in, const int* in_sizes, int n_in,
                              void* d_out, int out_size, void* d_ws, size_t ws_size,
                              hipStream_t stream) {
    const float* vf    = (const float*)d_in[0];  // [512,4096] f32
    const float* p_lfs = (const float*)d_in[1];  // [512,1024] f32
    const float* n_lfs = (const float*)d_in[2];  // [512,1024] f32
    const float* W     = (const float*)d_in[3];  // [1024,4096] f32
    const float* bias  = (const float*)d_in[4];  // [1024] f32
    float* out = (float*)d_out;                  // [512,513] f32

    // ws layout (22 MB peak):
    //   [0,  8MB): pg   f32 [KS=4,512,1024]  (dead after reduce_emb)
    //   [0,  8MB): pn   f32 [ES=8,512,512]   (overlays dead pg)
    //   [8, 12MB): vfB  bf16 [512,4096]
    //   [12,20MB): WB   bf16 [1024,4096]
    //   [20,22MB): emb  f32 [512,1024]
    char* ws = (char*)d_ws;
    float*          pg  = (float*)ws;
    float*          pn  = (float*)ws;
    unsigned short* vfB = (unsigned short*)(ws + ((size_t)8 << 20));
    unsigned short* WB  = (unsigned short*)(ws + ((size_t)12 << 20));
    float*          emb = (float*)(ws + ((size_t)20 << 20));

    cvt_all<<<3072, 256, 0, stream>>>(vf, W, vfB, WB);

    dim3 g1(E / 64, B / 64, KS);   // (16, 8, 4) = 512 one-wave blocks
    gemm_lds<<<g1, 64, 0, stream>>>(vfB, WB, pg);

    reduce_emb<<<(B * E) / 1024, 256, 0, stream>>>(pg, bias, emb);

    dim3 g3(N / 64, B / 64, ES);   // (8, 8, 8) = 512 blocks
    scores_part<<<g3, 256, 0, stream>>>(emb, n_lfs, pn);

    scores_final<<<1024 + B / 32, 256, 0, stream>>>(pn, emb, p_lfs, out);
}